// Round 2
// baseline (645.813 us; speedup 1.0000x reference)
//
#include <hip/hip_runtime.h>
#include <cstdint>
#include <cstddef>

// Problem constants: B=4, T=827, C=1024, NH=16, HS=64, SCALE=1/8
#define Tn  827
#define Cn  1024
#define BTn 3308      // B*T
#define TPn 832       // T padded to multiple of 32 (PV K-dim)
#define YSZ 3387392   // B*T*C  (y output elements)

typedef unsigned short u16;
typedef unsigned short u16x4 __attribute__((ext_vector_type(4)));
typedef __bf16 bf16_t;
typedef bf16_t bf16x8 __attribute__((ext_vector_type(8)));
typedef float f32x4 __attribute__((ext_vector_type(4)));

__device__ inline u16 f32_to_bf16(float f) {
  union { float f; unsigned u; } v; v.f = f;
  unsigned u = v.u;
  u += 0x7fffu + ((u >> 16) & 1u);   // RNE
  return (u16)(u >> 16);
}

// ---------------------------------------------------------------------------
// f32 -> bf16 conversion for x, x_kv, Wq, Wk, Wv, Wp (one fused launch)
// ---------------------------------------------------------------------------
__global__ __launch_bounds__(256)
void cvt_all_k(const float* __restrict__ x, const float* __restrict__ xkv,
               const float* __restrict__ wq, const float* __restrict__ wk,
               const float* __restrict__ wv, const float* __restrict__ wp,
               u16* __restrict__ xb, u16* __restrict__ xkb,
               u16* __restrict__ wqb, u16* __restrict__ wkb,
               u16* __restrict__ wvb, u16* __restrict__ wpb)
{
  const long NX = 846848;   // YSZ/4
  const long NW = 262144;   // C*C/4
  long qidx = (long)blockIdx.x * 256 + threadIdx.x;
  const float* s; u16* d; long base;
  if (qidx < NX)            { s = x;   d = xb;  base = qidx; }
  else if (qidx < 2 * NX)   { s = xkv; d = xkb; base = qidx - NX; }
  else {
    long w = qidx - 2 * NX;
    int wi = (int)(w / NW);
    base = w - (long)wi * NW;
    if      (wi == 0) { s = wq; d = wqb; }
    else if (wi == 1) { s = wk; d = wkb; }
    else if (wi == 2) { s = wv; d = wvb; }
    else if (wi == 3) { s = wp; d = wpb; }
    else return;
  }
  const float4 v = *(const float4*)(s + base * 4);
  u16x4 o;
  o.x = f32_to_bf16(v.x); o.y = f32_to_bf16(v.y);
  o.z = f32_to_bf16(v.z); o.w = f32_to_bf16(v.w);
  *(u16x4*)(d + base * 4) = o;
}

// ---------------------------------------------------------------------------
// Generic bf16 MFMA GEMM:  C = A(MxK, row-major, stride lda) . B(NxK)^T
// MODE 0: proj      -> Cb bf16, +bias
// MODE 1: scores    -> Cf fp32: Cf = acc*SCALE + Hadd (h read-only!)
//                      batched over z=(b,h); upper-diagonal tiles skipped
// MODE 2: PV        -> Cb bf16 scattered to (B,T,C) layout; K-loop truncated
// MODE 3: out proj  -> Cf fp32, +bias
// All inputs are strictly read-only; outputs live in d_ws / d_out.
// ---------------------------------------------------------------------------
template<int BM, int BN, int MODE>
__global__ __launch_bounds__(256)
void gemm_k(const u16* __restrict__ Aall, const u16* __restrict__ Ball,
            const float* __restrict__ bias, const float* __restrict__ Hadd,
            float* __restrict__ Cf, u16* __restrict__ Cb,
            int M, int N, int K, int lda, int ldb, int ldc)
{
  static_assert(BM == 128, "BM fixed at 128");
  constexpr int TM = BM / 32;   // 4
  constexpr int TN = BN / 32;   // 4 (BN=128) or 2 (BN=64)

  if constexpr (MODE == 1) {
    if (blockIdx.y > blockIdx.x) return;   // strictly-above-diagonal: never read
  }

  const int tid  = threadIdx.x;
  const int lane = tid & 63;
  const int wave = tid >> 6;
  const int wm = wave >> 1, wn = wave & 1;
  const int m0 = blockIdx.x * BM;
  const int n0 = blockIdx.y * BN;
  const int z  = blockIdx.z;

  const u16* Ab = Aall;
  const u16* Bb = Ball;
  if constexpr (MODE == 1) {
    const int b = z >> 4, hh = z & 15;
    Ab = Aall + ((size_t)b * Tn) * Cn + hh * 64;
    Bb = Ball + ((size_t)b * Tn) * Cn + hh * 64;
  } else if constexpr (MODE == 2) {
    Ab = Aall + (size_t)z * Tn * TPn;
    Bb = Ball + (size_t)z * 64 * TPn;
  }

  __shared__ u16 As[BM * 32];
  __shared__ u16 Bs[BN * 32];

  f32x4 acc[TM][TN];
  const f32x4 zero4 = {0.f, 0.f, 0.f, 0.f};
  #pragma unroll
  for (int i = 0; i < TM; ++i)
    #pragma unroll
    for (int j = 0; j < TN; ++j)
      acc[i][j] = zero4;

  int nk = K >> 5;
  if constexpr (MODE == 2) {
    // aw[m][k] == 0 for k > m: tiles with k0 > m0+BM-1 contribute nothing
    int lim = ((m0 + BM - 1) >> 5) + 1;
    if (lim < nk) nk = lim;
  }

  for (int kt = 0; kt < nk; ++kt) {
    const int k0 = kt << 5;
    __syncthreads();
    // ---- stage A tile (BM x 32 bf16) via async global->LDS, 16B/lane ----
    #pragma unroll
    for (int it = 0; it < BM / 64; ++it) {
      const int cbase = it * 256 + wave * 64;      // wave-uniform chunk base
      const int c  = cbase + lane;
      const int r  = c >> 2;
      const int ko = (c & 3) << 3;
      if (m0 + r < M)
        __builtin_amdgcn_global_load_lds(
            (__attribute__((address_space(1))) void*)(Ab + (size_t)(m0 + r) * lda + k0 + ko),
            (__attribute__((address_space(3))) void*)(As + cbase * 8),
            16, 0, 0);
    }
    // ---- stage B tile (BN x 32 bf16) ----
    #pragma unroll
    for (int it = 0; it < BN / 64; ++it) {
      const int cbase = it * 256 + wave * 64;
      const int c  = cbase + lane;
      const int r  = c >> 2;
      const int ko = (c & 3) << 3;
      if (n0 + r < N)
        __builtin_amdgcn_global_load_lds(
            (__attribute__((address_space(1))) void*)(Bb + (size_t)(n0 + r) * ldb + k0 + ko),
            (__attribute__((address_space(3))) void*)(Bs + cbase * 8),
            16, 0, 0);
    }
    __syncthreads();   // compiler emits vmcnt(0) drain before barrier

    bf16x8 af[TM], bfr[TN];
    #pragma unroll
    for (int i = 0; i < TM; ++i) {
      const int r = wm * 64 + i * 16 + (lane & 15);
      af[i] = *(const bf16x8*)(As + r * 32 + ((lane >> 4) << 3));
    }
    #pragma unroll
    for (int j = 0; j < TN; ++j) {
      const int r = wn * (TN * 16) + j * 16 + (lane & 15);
      bfr[j] = *(const bf16x8*)(Bs + r * 32 + ((lane >> 4) << 3));
    }
    #pragma unroll
    for (int i = 0; i < TM; ++i)
      #pragma unroll
      for (int j = 0; j < TN; ++j)
        acc[i][j] = __builtin_amdgcn_mfma_f32_16x16x32_bf16(af[i], bfr[j], acc[i][j], 0, 0, 0);
  }

  // ---- epilogue: D[row = quad*4+r][col = lane&15] ----
  const int cq = lane >> 4, cl = lane & 15;
  #pragma unroll
  for (int i = 0; i < TM; ++i) {
    #pragma unroll
    for (int j = 0; j < TN; ++j) {
      const int rb  = m0 + wm * 64 + i * 16 + cq * 4;
      const int col = n0 + wn * (TN * 16) + j * 16 + cl;
      #pragma unroll
      for (int r = 0; r < 4; ++r) {
        const int row = rb + r;
        const float v = acc[i][j][r];
        if constexpr (MODE == 0) {
          if (row < M) Cb[(size_t)row * ldc + col] = f32_to_bf16(v + bias[col]);
        } else if constexpr (MODE == 1) {
          if (row < M && col < N) {
            const size_t idx = (size_t)z * Tn * Tn + (size_t)row * Tn + col;
            Cf[idx] = v * 0.125f + Hadd[idx];   // att = q.k^T*SCALE + h (h read-only)
          }
        } else if constexpr (MODE == 2) {
          if (row < M) {
            const int b = z >> 4, hh = z & 15;
            Cb[((size_t)(b * Tn + row)) * Cn + hh * 64 + col] = f32_to_bf16(v);
          }
        } else {
          if (row < M) Cf[(size_t)row * ldc + col] = v + bias[col];
        }
      }
    }
  }
}

// ---------------------------------------------------------------------------
// V (B,T,C) bf16 -> Vt (B*NH, 64, TPn) bf16 (zero-padded k >= T)
// ---------------------------------------------------------------------------
__global__ __launch_bounds__(256)
void vtrans_k(const u16* __restrict__ V, u16* __restrict__ Vt)
{
  const int z = blockIdx.y;
  const int b = z >> 4, hh = z & 15;
  const int k0 = blockIdx.x * 64;
  const int tid = threadIdx.x;
  __shared__ u16 tile[64 * 65];
  #pragma unroll
  for (int rep = 0; rep < 16; ++rep) {
    const int idx = rep * 256 + tid;
    const int kl = idx >> 6, n = idx & 63;
    const int k = k0 + kl;
    u16 val = 0;
    if (k < Tn) val = V[((size_t)(b * Tn + k)) * Cn + hh * 64 + n];
    tile[n * 65 + kl] = val;
  }
  __syncthreads();
  #pragma unroll
  for (int rep = 0; rep < 16; ++rep) {
    const int idx = rep * 256 + tid;
    const int n = idx >> 6, kl = idx & 63;
    const int k = k0 + kl;
    if (k < TPn) Vt[((size_t)z * 64 + n) * TPn + k] = tile[n * 65 + kl];
  }
}

// ---------------------------------------------------------------------------
// Regional softmax / stats / multiply / second softmax. One wave per row.
// region 0: q in [285,541), cols [0,256):    att = softmax(s) * b01^T*f01
// region 1: q in [571,827), cols [0,256):    att = softmax(softmax(s)*b02^T*f02)
// region 2: q in [571,827), cols [286,542):  stats from softmax(s), then
//                                            att = softmax(softmax(s)*b12^T*f12)
// Operates on S (in d_ws), NOT on the h input.
// ---------------------------------------------------------------------------
__global__ __launch_bounds__(256)
void regional_k(float* __restrict__ att,
                const float* __restrict__ f01, const float* __restrict__ f02,
                const float* __restrict__ f12, const float* __restrict__ b01,
                const float* __restrict__ b02, const float* __restrict__ b12,
                float* __restrict__ mmOut, float* __restrict__ amOut)
{
  const int tid  = threadIdx.x;
  const int lane = tid & 63;
  const int wrow = tid >> 6;
  const int row_id = blockIdx.x * 4 + wrow;      // 0 .. 49151
  const int region = row_id >> 14;               // / 16384
  const int rr = row_id & 16383;
  const int b  = rr >> 12;
  const int hh = (rr >> 8) & 15;
  const int i  = rr & 255;
  const int q     = (region == 0) ? (285 + i) : (571 + i);
  const int kbase = (region == 2) ? 286 : 0;
  float* rp = att + (((size_t)(b * 16 + hh)) * Tn + q) * Tn + kbase;

  const float* fp = (region == 0) ? f01 : (region == 1) ? f02 : f12;
  const float* bp = (region == 0) ? b01 : (region == 1) ? b02 : b12;

  float v[4], fv[4], bv[4];
  #pragma unroll
  for (int t = 0; t < 4; ++t) {
    const int j = lane + 64 * t;
    v[t]  = rp[j];
    fv[t] = fp[((size_t)b * 256 + i) * 256 + j];
    bv[t] = bp[((size_t)b * 256 + j) * 256 + i];
  }
  // softmax over the 256 columns
  float mx = fmaxf(fmaxf(v[0], v[1]), fmaxf(v[2], v[3]));
  for (int m = 32; m > 0; m >>= 1) mx = fmaxf(mx, __shfl_xor(mx, m));
  float e[4], s = 0.f;
  #pragma unroll
  for (int t = 0; t < 4; ++t) { e[t] = __expf(v[t] - mx); s += e[t]; }
  for (int m = 32; m > 0; m >>= 1) s += __shfl_xor(s, m);
  const float inv = 1.f / s;
  float sm[4];
  #pragma unroll
  for (int t = 0; t < 4; ++t) sm[t] = e[t] * inv;

  if (region == 2) {
    float msum = 0.f, mcnt = 0.f, asum = 0.f;
    #pragma unroll
    for (int t = 0; t < 4; ++t) {
      const float mk = (fv[t] * bv[t] >= 0.1f) ? 1.f : 0.f;
      msum += sm[t] * mk; mcnt += mk; asum += sm[t];
    }
    for (int m = 32; m > 0; m >>= 1) {
      msum += __shfl_xor(msum, m);
      mcnt += __shfl_xor(mcnt, m);
      asum += __shfl_xor(asum, m);
    }
    if (lane == 0) {
      const int idx = (b * 16 + hh) * 256 + i;
      mmOut[idx] = msum / mcnt;
      amOut[idx] = asum * (1.f / 256.f);
    }
  }

  float mult[4];
  #pragma unroll
  for (int t = 0; t < 4; ++t) mult[t] = sm[t] * fv[t] * bv[t];

  if (region == 0) {
    #pragma unroll
    for (int t = 0; t < 4; ++t) rp[lane + 64 * t] = mult[t];
  } else {
    float mx2 = fmaxf(fmaxf(mult[0], mult[1]), fmaxf(mult[2], mult[3]));
    for (int m = 32; m > 0; m >>= 1) mx2 = fmaxf(mx2, __shfl_xor(mx2, m));
    float e2[4], s2 = 0.f;
    #pragma unroll
    for (int t = 0; t < 4; ++t) { e2[t] = __expf(mult[t] - mx2); s2 += e2[t]; }
    for (int m = 32; m > 0; m >>= 1) s2 += __shfl_xor(s2, m);
    const float inv2 = 1.f / s2;
    #pragma unroll
    for (int t = 0; t < 4; ++t) rp[lane + 64 * t] = e2[t] * inv2;
  }
}

// ---------------------------------------------------------------------------
// Final causal row softmax over the (modified) score matrix -> aw (bf16,
// K-padded to TPn with zeros). One block per (b,h,q) row.
// ---------------------------------------------------------------------------
__global__ __launch_bounds__(256)
void rowsm_k(const float* __restrict__ att, u16* __restrict__ aw)
{
  const int rowid = blockIdx.x;            // 0 .. B*NH*T-1
  const int z = rowid / Tn;
  const int q = rowid - z * Tn;
  const float* rp = att + (size_t)rowid * Tn;
  u16* op = aw + (size_t)rowid * TPn;
  const int tid = threadIdx.x;
  const int lane = tid & 63, wave = tid >> 6;
  __shared__ float redm[4], reds[4];

  float vals[4];
  float mx = -3.0e38f;
  #pragma unroll
  for (int t = 0; t < 4; ++t) {
    const int k = tid + 256 * t;
    if (k <= q) { vals[t] = rp[k]; mx = fmaxf(mx, vals[t]); }
  }
  for (int m = 32; m > 0; m >>= 1) mx = fmaxf(mx, __shfl_xor(mx, m));
  if (lane == 0) redm[wave] = mx;
  __syncthreads();
  mx = fmaxf(fmaxf(redm[0], redm[1]), fmaxf(redm[2], redm[3]));

  float ex[4], s = 0.f;
  #pragma unroll
  for (int t = 0; t < 4; ++t) {
    const int k = tid + 256 * t;
    if (k <= q) { ex[t] = __expf(vals[t] - mx); s += ex[t]; }
    else ex[t] = 0.f;
  }
  for (int m = 32; m > 0; m >>= 1) s += __shfl_xor(s, m);
  if (lane == 0) reds[wave] = s;
  __syncthreads();
  s = reds[0] + reds[1] + reds[2] + reds[3];
  const float inv = 1.f / s;

  #pragma unroll
  for (int t = 0; t < 4; ++t) {
    const int k = tid + 256 * t;
    if (k < TPn) op[k] = f32_to_bf16(ex[t] * inv);
  }
}

// ---------------------------------------------------------------------------
// bi_epi_ratio[b,i] = sum_h(mask_mean) / sum_h(mean)
// ---------------------------------------------------------------------------
__global__ __launch_bounds__(256)
void ratio_k(const float* __restrict__ mm, const float* __restrict__ am,
             float* __restrict__ out)
{
  const int idx = blockIdx.x * 256 + threadIdx.x;   // 0..1023
  const int b = idx >> 8, i = idx & 255;
  float smm = 0.f, sam = 0.f;
  #pragma unroll
  for (int hh = 0; hh < 16; ++hh) {
    smm += mm[(b * 16 + hh) * 256 + i];
    sam += am[(b * 16 + hh) * 256 + i];
  }
  out[idx] = smm / sam;
}

// ---------------------------------------------------------------------------
extern "C" void kernel_launch(void* const* d_in, const int* in_sizes, int n_in,
                              void* d_out, int out_size, void* d_ws, size_t ws_size,
                              hipStream_t stream)
{
  (void)in_sizes; (void)n_in; (void)out_size;

  const float* x   = (const float*)d_in[0];
  const float* xkv = (const float*)d_in[1];
  const float* hb  = (const float*)d_in[2];   // READ-ONLY now
  const float* f01 = (const float*)d_in[3];
  const float* f02 = (const float*)d_in[4];
  const float* f12 = (const float*)d_in[5];
  const float* b01 = (const float*)d_in[6];
  const float* b02 = (const float*)d_in[7];
  const float* b12 = (const float*)d_in[8];
  const float* Wq  = (const float*)d_in[9];
  const float* Wk  = (const float*)d_in[10];
  const float* Wv  = (const float*)d_in[11];
  const float* Wp  = (const float*)d_in[12];
  const float* bq  = (const float*)d_in[13];
  const float* bk  = (const float*)d_in[14];
  const float* bv  = (const float*)d_in[15];
  const float* bp  = (const float*)d_in[16];
  float* out = (float*)d_out;

  // ---- workspace layout with lifetime-based overlays (~260 MiB peak) ----
  // S region [0, 175,085,824): scores fp32 (steps 4-6).
  //   Before step 4 it holds xb/xkb/wqb/wkb/wvb/Vb (all dead by step 4).
  //   After step 6 its head holds ya (step 7-8).
  // aw region [S_end, +88,072,192): aw bf16 (steps 6-7).
  //   Before step 6 it holds Qb/Kb (dead after step 4).
  // Then: Vt, wpb, mm, am (dedicated).
  char* ws = (char*)d_ws;
  float* S  = (float*)ws;
  u16* xb   = (u16*)(ws + 0);
  u16* xkb  = (u16*)(ws + 6774784);
  u16* wqb  = (u16*)(ws + 13549568);
  u16* wkb  = (u16*)(ws + 15646720);
  u16* wvb  = (u16*)(ws + 17743872);
  u16* Vb   = (u16*)(ws + 19841024);
  u16* ya   = (u16*)(ws + 0);
  const size_t AWO = 175085824;          // 64*827*827*4
  u16* aw   = (u16*)(ws + AWO);
  u16* Qb   = (u16*)(ws + AWO);
  u16* Kb   = (u16*)(ws + AWO + 6774784);
  const size_t VTO = AWO + 88072192;     // 263,158,016
  u16* Vt   = (u16*)(ws + VTO);
  const size_t WPO = VTO + 6815744;      // 269,973,760
  u16* wpb  = (u16*)(ws + WPO);
  const size_t MMO = WPO + 2097152;      // 272,070,912
  float* mm = (float*)(ws + MMO);
  float* am = (float*)(ws + MMO + 65536);
  const size_t need = MMO + 131072;      // 272,201,984 B (~259.6 MiB)
  if (ws_size < need) return;            // call-invariant; leaves out poisoned

  // 1) convert inputs/weights to bf16
  cvt_all_k<<<dim3(10712), 256, 0, stream>>>(x, xkv, Wq, Wk, Wv, Wp,
                                             xb, xkb, wqb, wkb, wvb, wpb);
  // 2) projections (bf16 MFMA, fp32 acc, +bias, bf16 out); 128x64 tiles -> 416 blocks
  gemm_k<128,64,0><<<dim3(26,16,1),256,0,stream>>>(xb,  wqb, bq, nullptr, nullptr, Qb, BTn, Cn, Cn, Cn, Cn, Cn);
  gemm_k<128,64,0><<<dim3(26,16,1),256,0,stream>>>(xkb, wkb, bk, nullptr, nullptr, Kb, BTn, Cn, Cn, Cn, Cn, Cn);
  gemm_k<128,64,0><<<dim3(26,16,1),256,0,stream>>>(xkb, wvb, bv, nullptr, nullptr, Vb, BTn, Cn, Cn, Cn, Cn, Cn);
  // 3) V transpose for PV B-operand
  vtrans_k<<<dim3(13,64),256,0,stream>>>(Vb, Vt);
  // 4) S = Q.K^T*SCALE + h  (h strictly read-only; upper-diagonal tiles skipped)
  gemm_k<128,128,1><<<dim3(7,7,64),256,0,stream>>>(Qb, Kb, nullptr, hb, S, nullptr, Tn, Tn, 64, Cn, Cn, Tn);
  // 5) regional softmaxes + bi_epi stats + factor multiplies + second softmaxes
  regional_k<<<dim3(12288),256,0,stream>>>(S, f01, f02, f12, b01, b02, b12, mm, am);
  // 6) causal row softmax -> aw bf16 (zero-padded)
  rowsm_k<<<dim3(64 * Tn),256,0,stream>>>(S, aw);
  // 7) y_att = aw . V   (scattered bf16 store into (B,T,C) layout)
  gemm_k<128,64,2><<<dim3(7,1,64),256,0,stream>>>(aw, Vt, nullptr, nullptr, nullptr, ya, Tn, 64, TPn, TPn, TPn, 0);
  // 8) y = y_att . Wp^T + bp -> d_out (fp32)
  gemm_k<128,64,3><<<dim3(26,16,1),256,0,stream>>>(ya, wpb, bp, nullptr, out, nullptr, BTn, Cn, Cn, Cn, Cn, Cn);
  // 9) bi_epi_ratio -> d_out tail
  ratio_k<<<dim3(4),256,0,stream>>>(mm, am, out + YSZ);
}

// Round 3
// 472.755 us; speedup vs baseline: 1.3661x; 1.3661x over previous
//
#include <hip/hip_runtime.h>
#include <cstdint>
#include <cstddef>

// Problem constants: B=4, T=827, C=1024, NH=16, HS=64, SCALE=1/8
#define Tn  827
#define Cn  1024
#define BTn 3308      // B*T
#define TPn 832       // T padded to multiple of 32/64
#define YSZ 3387392   // B*T*C  (y output elements)

typedef unsigned short u16;
typedef unsigned short u16x4 __attribute__((ext_vector_type(4)));
typedef __bf16 bf16_t;
typedef bf16_t bf16x8 __attribute__((ext_vector_type(8)));
typedef float f32x4 __attribute__((ext_vector_type(4)));

__device__ inline u16 f32_to_bf16(float f) {
  union { float f; unsigned u; } v; v.f = f;
  unsigned u = v.u;
  u += 0x7fffu + ((u >> 16) & 1u);   // RNE
  return (u16)(u >> 16);
}

// ---------------------------------------------------------------------------
// f32 -> bf16 conversion for x, x_kv, Wq, Wk, Wv, Wp (one fused launch)
// ---------------------------------------------------------------------------
__global__ __launch_bounds__(256)
void cvt_all_k(const float* __restrict__ x, const float* __restrict__ xkv,
               const float* __restrict__ wq, const float* __restrict__ wk,
               const float* __restrict__ wv, const float* __restrict__ wp,
               u16* __restrict__ xb, u16* __restrict__ xkb,
               u16* __restrict__ wqb, u16* __restrict__ wkb,
               u16* __restrict__ wvb, u16* __restrict__ wpb)
{
  const long NX = 846848;   // YSZ/4
  const long NW = 262144;   // C*C/4
  long qidx = (long)blockIdx.x * 256 + threadIdx.x;
  const float* s; u16* d; long base;
  if (qidx < NX)            { s = x;   d = xb;  base = qidx; }
  else if (qidx < 2 * NX)   { s = xkv; d = xkb; base = qidx - NX; }
  else {
    long w = qidx - 2 * NX;
    int wi = (int)(w / NW);
    base = w - (long)wi * NW;
    if      (wi == 0) { s = wq; d = wqb; }
    else if (wi == 1) { s = wk; d = wkb; }
    else if (wi == 2) { s = wv; d = wvb; }
    else if (wi == 3) { s = wp; d = wpb; }
    else return;
  }
  const float4 v = *(const float4*)(s + base * 4);
  u16x4 o;
  o.x = f32_to_bf16(v.x); o.y = f32_to_bf16(v.y);
  o.z = f32_to_bf16(v.z); o.w = f32_to_bf16(v.w);
  *(u16x4*)(d + base * 4) = o;
}

// ---------------------------------------------------------------------------
// bf16 MFMA GEMM:  C = A(MxK) . B(NxK)^T    (m97 structure, BK=32)
// MODE 0: proj     -> Cb bf16, +bias
// MODE 3: out proj -> Cf fp32, +bias
// ---------------------------------------------------------------------------
template<int BM, int BN, int MODE>
__global__ __launch_bounds__(256)
void gemm_k(const u16* __restrict__ Aall, const u16* __restrict__ Ball,
            const float* __restrict__ bias, float* __restrict__ Cf,
            u16* __restrict__ Cb, int M, int N, int K, int lda, int ldb, int ldc)
{
  static_assert(BM == 128, "BM fixed at 128");
  constexpr int TM = BM / 32;   // 4
  constexpr int TN = BN / 32;   // 2 (BN=64)

  const int tid  = threadIdx.x;
  const int lane = tid & 63;
  const int wave = tid >> 6;
  const int wm = wave >> 1, wn = wave & 1;
  const int m0 = blockIdx.x * BM;
  const int n0 = blockIdx.y * BN;

  __shared__ u16 As[BM * 32];
  __shared__ u16 Bs[BN * 32];

  f32x4 acc[TM][TN];
  const f32x4 zero4 = {0.f, 0.f, 0.f, 0.f};
  #pragma unroll
  for (int i = 0; i < TM; ++i)
    #pragma unroll
    for (int j = 0; j < TN; ++j)
      acc[i][j] = zero4;

  const int nk = K >> 5;

  for (int kt = 0; kt < nk; ++kt) {
    const int k0 = kt << 5;
    __syncthreads();
    #pragma unroll
    for (int it = 0; it < BM / 64; ++it) {
      const int cbase = it * 256 + wave * 64;
      const int c  = cbase + lane;
      const int r  = c >> 2;
      const int ko = (c & 3) << 3;
      if (m0 + r < M)
        __builtin_amdgcn_global_load_lds(
            (__attribute__((address_space(1))) void*)(Aall + (size_t)(m0 + r) * lda + k0 + ko),
            (__attribute__((address_space(3))) void*)(As + cbase * 8),
            16, 0, 0);
    }
    #pragma unroll
    for (int it = 0; it < BN / 64; ++it) {
      const int cbase = it * 256 + wave * 64;
      const int c  = cbase + lane;
      const int r  = c >> 2;
      const int ko = (c & 3) << 3;
      if (n0 + r < N)
        __builtin_amdgcn_global_load_lds(
            (__attribute__((address_space(1))) void*)(Ball + (size_t)(n0 + r) * ldb + k0 + ko),
            (__attribute__((address_space(3))) void*)(Bs + cbase * 8),
            16, 0, 0);
    }
    __syncthreads();

    bf16x8 af[TM], bfr[TN];
    #pragma unroll
    for (int i = 0; i < TM; ++i) {
      const int r = wm * 64 + i * 16 + (lane & 15);
      af[i] = *(const bf16x8*)(As + r * 32 + ((lane >> 4) << 3));
    }
    #pragma unroll
    for (int j = 0; j < TN; ++j) {
      const int r = wn * (TN * 16) + j * 16 + (lane & 15);
      bfr[j] = *(const bf16x8*)(Bs + r * 32 + ((lane >> 4) << 3));
    }
    #pragma unroll
    for (int i = 0; i < TM; ++i)
      #pragma unroll
      for (int j = 0; j < TN; ++j)
        acc[i][j] = __builtin_amdgcn_mfma_f32_16x16x32_bf16(af[i], bfr[j], acc[i][j], 0, 0, 0);
  }

  const int cq = lane >> 4, cl = lane & 15;
  #pragma unroll
  for (int i = 0; i < TM; ++i) {
    #pragma unroll
    for (int j = 0; j < TN; ++j) {
      const int rb  = m0 + wm * 64 + i * 16 + cq * 4;
      const int col = n0 + wn * (TN * 16) + j * 16 + cl;
      #pragma unroll
      for (int r = 0; r < 4; ++r) {
        const int row = rb + r;
        const float v = acc[i][j][r];
        if constexpr (MODE == 0) {
          if (row < M) Cb[(size_t)row * ldc + col] = f32_to_bf16(v + bias[col]);
        } else {
          if (row < M) Cf[(size_t)row * ldc + col] = v + bias[col];
        }
      }
    }
  }
}

// ---------------------------------------------------------------------------
// V (B,T,C) bf16 -> Vt (B*NH, 64, TPn) bf16 (zero-padded k >= T)
// ---------------------------------------------------------------------------
__global__ __launch_bounds__(256)
void vtrans_k(const u16* __restrict__ V, u16* __restrict__ Vt)
{
  const int z = blockIdx.y;
  const int b = z >> 4, hh = z & 15;
  const int k0 = blockIdx.x * 64;
  const int tid = threadIdx.x;
  __shared__ u16 tile[64 * 65];
  #pragma unroll
  for (int rep = 0; rep < 16; ++rep) {
    const int idx = rep * 256 + tid;
    const int kl = idx >> 6, n = idx & 63;
    const int k = k0 + kl;
    u16 val = 0;
    if (k < Tn) val = V[((size_t)(b * Tn + k)) * Cn + hh * 64 + n];
    tile[n * 65 + kl] = val;
  }
  __syncthreads();
  #pragma unroll
  for (int rep = 0; rep < 16; ++rep) {
    const int idx = rep * 256 + tid;
    const int n = idx >> 6, kl = idx & 63;
    const int k = k0 + kl;
    if (k < TPn) Vt[((size_t)z * 64 + n) * TPn + k] = tile[n * 65 + kl];
  }
}

// ---------------------------------------------------------------------------
// b01/b02/b12 -> transposed copies bT[rg*4+b][256][256] with [i][j]=b[b][j][i]
// ---------------------------------------------------------------------------
__global__ __launch_bounds__(256)
void btrans_k(const float* __restrict__ b01, const float* __restrict__ b02,
              const float* __restrict__ b12, float* __restrict__ bT)
{
  const int mb = blockIdx.z;       // rg*4 + b
  const int rg = mb >> 2, bb = mb & 3;
  const float* src = (rg == 0 ? b01 : rg == 1 ? b02 : b12) + (size_t)bb * 65536;
  float* dst = bT + (size_t)mb * 65536;
  const int i0 = blockIdx.x * 64, j0 = blockIdx.y * 64;
  __shared__ float tile[64 * 65];
  const int tid = threadIdx.x;
  #pragma unroll
  for (int rep = 0; rep < 16; ++rep) {
    const int idx = rep * 256 + tid;
    const int jj = idx >> 6, ii = idx & 63;
    tile[ii * 65 + jj] = src[(size_t)(j0 + jj) * 256 + i0 + ii];
  }
  __syncthreads();
  #pragma unroll
  for (int rep = 0; rep < 16; ++rep) {
    const int idx = rep * 256 + tid;
    const int ii = idx >> 6, jj = idx & 63;
    dst[(size_t)(i0 + ii) * 256 + j0 + jj] = tile[ii * 65 + jj];
  }
}

// ---------------------------------------------------------------------------
// Regional score blocks: Sreg[z*3+rg][256][256] = Q.K^T*SCALE + h
// rg 0: q 285+, k 0+ | rg 1: q 571+, k 0+ | rg 2: q 571+, k 286+
// 64x64 tiles; h-loads hoisted (batched) before stores.
// ---------------------------------------------------------------------------
__global__ __launch_bounds__(256)
void sreg_k(const u16* __restrict__ Qb, const u16* __restrict__ Kb,
            const float* __restrict__ hsrc, float* __restrict__ Sreg)
{
  const int zr = blockIdx.z;          // z*3+rg
  const int rg = zr % 3;
  const int z  = zr / 3;
  const int b = z >> 4, hh = z & 15;
  const int qoff = (rg == 0) ? 285 : 571;
  const int koff = (rg == 2) ? 286 : 0;
  const int m0 = blockIdx.x * 64;
  const int n0 = blockIdx.y * 64;

  const int tid = threadIdx.x;
  const int lane = tid & 63, wave = tid >> 6;
  const int quad = lane >> 4, cl = lane & 15;
  const int wm = wave >> 1, wn = wave & 1;

  __shared__ u16 As[2048], Bs[2048];

  const u16* Ab = Qb + ((size_t)(b * Tn + qoff + m0)) * Cn + hh * 64;
  const u16* Bb = Kb + ((size_t)(b * Tn + koff + n0)) * Cn + hh * 64;

  f32x4 acc[2][2];
  const f32x4 zero4 = {0.f, 0.f, 0.f, 0.f};
  acc[0][0] = zero4; acc[0][1] = zero4; acc[1][0] = zero4; acc[1][1] = zero4;

  #pragma unroll
  for (int kt = 0; kt < 2; ++kt) {
    const int k0 = kt * 32;
    __syncthreads();
    const int r = tid >> 2, ko = (tid & 3) << 3;
    __builtin_amdgcn_global_load_lds(
        (__attribute__((address_space(1))) void*)(Ab + (size_t)r * Cn + k0 + ko),
        (__attribute__((address_space(3))) void*)(&As[wave * 512]), 16, 0, 0);
    __builtin_amdgcn_global_load_lds(
        (__attribute__((address_space(1))) void*)(Bb + (size_t)r * Cn + k0 + ko),
        (__attribute__((address_space(3))) void*)(&Bs[wave * 512]), 16, 0, 0);
    __syncthreads();
    bf16x8 af[2], bfr[2];
    #pragma unroll
    for (int i = 0; i < 2; ++i)
      af[i] = *(const bf16x8*)(&As[(wm * 32 + i * 16 + cl) * 32 + quad * 8]);
    #pragma unroll
    for (int j = 0; j < 2; ++j)
      bfr[j] = *(const bf16x8*)(&Bs[(wn * 32 + j * 16 + cl) * 32 + quad * 8]);
    #pragma unroll
    for (int i = 0; i < 2; ++i)
      #pragma unroll
      for (int j = 0; j < 2; ++j)
        acc[i][j] = __builtin_amdgcn_mfma_f32_16x16x32_bf16(af[i], bfr[j], acc[i][j], 0, 0, 0);
  }

  // batched h loads (all 16 in flight), then 16 stores
  float hvv[2][2][4];
  const size_t hb0 = (size_t)z * Tn * Tn;
  #pragma unroll
  for (int i = 0; i < 2; ++i)
    #pragma unroll
    for (int j = 0; j < 2; ++j)
      #pragma unroll
      for (int r = 0; r < 4; ++r) {
        const int row = m0 + wm * 32 + i * 16 + quad * 4 + r;
        const int col = n0 + wn * 32 + j * 16 + cl;
        hvv[i][j][r] = hsrc[hb0 + (size_t)(qoff + row) * Tn + koff + col];
      }
  float* outb = Sreg + ((size_t)zr << 16);
  #pragma unroll
  for (int i = 0; i < 2; ++i)
    #pragma unroll
    for (int j = 0; j < 2; ++j)
      #pragma unroll
      for (int r = 0; r < 4; ++r) {
        const int row = m0 + wm * 32 + i * 16 + quad * 4 + r;
        const int col = n0 + wn * 32 + j * 16 + cl;
        outb[(size_t)row * 256 + col] = acc[i][j][r] * 0.125f + hvv[i][j][r];
      }
}

// ---------------------------------------------------------------------------
// Regional softmax / stats / multiply / second softmax on Sreg. One wave/row.
// ---------------------------------------------------------------------------
__global__ __launch_bounds__(256)
void regional_k(float* __restrict__ Sreg, const float* __restrict__ f01,
                const float* __restrict__ f02, const float* __restrict__ f12,
                const float* __restrict__ bT,
                float* __restrict__ mmOut, float* __restrict__ amOut)
{
  const int tid  = threadIdx.x;
  const int lane = tid & 63;
  const int wrow = tid >> 6;
  const int row_id = blockIdx.x * 4 + wrow;      // 0 .. 49151
  const int region = row_id >> 14;
  const int rr = row_id & 16383;
  const int b  = rr >> 12;
  const int hh = (rr >> 8) & 15;
  const int i  = rr & 255;
  float* rp = Sreg + ((size_t)(((b * 16 + hh) * 3) + region) << 16) + (size_t)i * 256;

  const float* fp = (region == 0) ? f01 : (region == 1) ? f02 : f12;
  const float* bp = bT + ((size_t)(region * 4 + b) << 16);

  float v[4], fv[4], bv[4];
  #pragma unroll
  for (int t = 0; t < 4; ++t) {
    const int j = lane + 64 * t;
    v[t]  = rp[j];
    fv[t] = fp[((size_t)b * 256 + i) * 256 + j];
    bv[t] = bp[(size_t)i * 256 + j];
  }
  float mx = fmaxf(fmaxf(v[0], v[1]), fmaxf(v[2], v[3]));
  for (int m = 32; m > 0; m >>= 1) mx = fmaxf(mx, __shfl_xor(mx, m));
  float e[4], s = 0.f;
  #pragma unroll
  for (int t = 0; t < 4; ++t) { e[t] = __expf(v[t] - mx); s += e[t]; }
  for (int m = 32; m > 0; m >>= 1) s += __shfl_xor(s, m);
  const float inv = 1.f / s;
  float sm[4];
  #pragma unroll
  for (int t = 0; t < 4; ++t) sm[t] = e[t] * inv;

  if (region == 2) {
    float msum = 0.f, mcnt = 0.f, asum = 0.f;
    #pragma unroll
    for (int t = 0; t < 4; ++t) {
      const float mk = (fv[t] * bv[t] >= 0.1f) ? 1.f : 0.f;
      msum += sm[t] * mk; mcnt += mk; asum += sm[t];
    }
    for (int m = 32; m > 0; m >>= 1) {
      msum += __shfl_xor(msum, m);
      mcnt += __shfl_xor(mcnt, m);
      asum += __shfl_xor(asum, m);
    }
    if (lane == 0) {
      const int idx = (b * 16 + hh) * 256 + i;
      mmOut[idx] = msum / mcnt;
      amOut[idx] = asum * (1.f / 256.f);
    }
  }

  float mult[4];
  #pragma unroll
  for (int t = 0; t < 4; ++t) mult[t] = sm[t] * fv[t] * bv[t];

  if (region == 0) {
    #pragma unroll
    for (int t = 0; t < 4; ++t) rp[lane + 64 * t] = mult[t];
  } else {
    float mx2 = fmaxf(fmaxf(mult[0], mult[1]), fmaxf(mult[2], mult[3]));
    for (int m = 32; m > 0; m >>= 1) mx2 = fmaxf(mx2, __shfl_xor(mx2, m));
    float e2[4], s2 = 0.f;
    #pragma unroll
    for (int t = 0; t < 4; ++t) { e2[t] = __expf(mult[t] - mx2); s2 += e2[t]; }
    for (int m = 32; m > 0; m >>= 1) s2 += __shfl_xor(s2, m);
    const float inv2 = 1.f / s2;
    #pragma unroll
    for (int t = 0; t < 4; ++t) rp[lane + 64 * t] = e2[t] * inv2;
  }
}

// ---------------------------------------------------------------------------
// Fused flash attention: per 64-row q-tile, stream 64-col k-tiles:
//   s = Q.K^T*SCALE + h   (or Sreg overlay at regional positions)
//   causal online softmax; O += P.V ; final O/l -> ya (B,T,C bf16)
// Block mapping keeps each z's K/V on one XCD: bid%8 == z%8.
// ---------------------------------------------------------------------------
__global__ __launch_bounds__(256)
void flash_k(const u16* __restrict__ Qb, const u16* __restrict__ Kb,
             const u16* __restrict__ Vt, const float* __restrict__ hsrc,
             const float* __restrict__ Sreg, u16* __restrict__ ya)
{
  const int bid = blockIdx.x;          // 0..831
  const int zlow = bid & 7;
  const int t = bid >> 3;              // 0..103
  const int qt = t % 13;
  const int zhigh = t / 13;
  const int z = zhigh * 8 + zlow;
  const int b = z >> 4, hh = z & 15;
  const int q0 = qt * 64;

  const int tid = threadIdx.x;
  const int lane = tid & 63;
  const int wave = tid >> 6;
  const int quad = lane >> 4;
  const int cl = lane & 15;

  __shared__ u16 Qs[2][2048];
  __shared__ u16 Ks[2][2048];
  __shared__ u16 Vs[2][2048];
  __shared__ u16 Ps[4][2][512];

  // ---- stage Q once (two 32-col panels) ----
  {
    const u16* src = Qb + ((size_t)(b * Tn + q0)) * Cn + hh * 64;
    const int r = tid >> 2;
    const int ko = (tid & 3) << 3;
    #pragma unroll
    for (int p = 0; p < 2; ++p)
      __builtin_amdgcn_global_load_lds(
          (__attribute__((address_space(1))) void*)(src + (size_t)r * Cn + p * 32 + ko),
          (__attribute__((address_space(3))) void*)(&Qs[p][wave * 512]), 16, 0, 0);
  }
  __syncthreads();

  bf16x8 qa[2];
  #pragma unroll
  for (int p = 0; p < 2; ++p)
    qa[p] = *(const bf16x8*)(&Qs[p][(wave * 16 + cl) * 32 + quad * 8]);

  f32x4 Oa[4];
  const f32x4 zero4 = {0.f, 0.f, 0.f, 0.f};
  Oa[0] = zero4; Oa[1] = zero4; Oa[2] = zero4; Oa[3] = zero4;
  float mrow[4] = {-3.0e38f, -3.0e38f, -3.0e38f, -3.0e38f};
  float lrow[4] = {0.f, 0.f, 0.f, 0.f};

  const size_t hbase = (size_t)z * Tn * Tn;
  const int qrow_base = q0 + wave * 16 + quad * 4;

  for (int kt = 0; kt <= qt; ++kt) {
    const int k0 = kt * 64;
    __syncthreads();
    {
      const u16* ksrc = Kb + ((size_t)(b * Tn + k0)) * Cn + hh * 64;
      const u16* vsrc = Vt + ((size_t)(z * 64)) * TPn + k0;
      const int r = tid >> 2;
      const int ko = (tid & 3) << 3;
      #pragma unroll
      for (int p = 0; p < 2; ++p) {
        __builtin_amdgcn_global_load_lds(
            (__attribute__((address_space(1))) void*)(ksrc + (size_t)r * Cn + p * 32 + ko),
            (__attribute__((address_space(3))) void*)(&Ks[p][wave * 512]), 16, 0, 0);
        __builtin_amdgcn_global_load_lds(
            (__attribute__((address_space(1))) void*)(vsrc + (size_t)r * TPn + p * 32 + ko),
            (__attribute__((address_space(3))) void*)(&Vs[p][wave * 512]), 16, 0, 0);
      }
    }
    // h / Sreg gather — issued now, in flight with the LDS staging
    float hv[4][4];
    unsigned rmask = 0;
    #pragma unroll
    for (int j = 0; j < 4; ++j) {
      const int kk = k0 + j * 16 + cl;
      #pragma unroll
      for (int r = 0; r < 4; ++r) {
        const int qq = qrow_base + r;
        const float* p = hsrc + hbase + (size_t)qq * Tn + kk;
        bool isreg = false;
        if (kk < 542) {
          if (qq >= 571 && qq < Tn) {
            if (kk < 256) {
              p = Sreg + (((size_t)(z * 3 + 1)) << 16) + (size_t)(qq - 571) * 256 + kk;
              isreg = true;
            } else if (kk >= 286) {
              p = Sreg + (((size_t)(z * 3 + 2)) << 16) + (size_t)(qq - 571) * 256 + (kk - 286);
              isreg = true;
            }
          } else if (qq >= 285 && qq < 541 && kk < 256) {
            p = Sreg + (((size_t)(z * 3 + 0)) << 16) + (size_t)(qq - 285) * 256 + kk;
            isreg = true;
          }
        }
        const bool valid = (kk <= qq) && (qq < Tn);
        hv[j][r] = valid ? *p : 0.f;
        if (isreg) rmask |= 1u << (j * 4 + r);
      }
    }
    __syncthreads();

    // ---- s = Q.K^T ----
    f32x4 sa[4];
    sa[0] = zero4; sa[1] = zero4; sa[2] = zero4; sa[3] = zero4;
    #pragma unroll
    for (int p = 0; p < 2; ++p) {
      #pragma unroll
      for (int n = 0; n < 4; ++n) {
        const bf16x8 kb = *(const bf16x8*)(&Ks[p][(n * 16 + cl) * 32 + quad * 8]);
        sa[n] = __builtin_amdgcn_mfma_f32_16x16x32_bf16(qa[p], kb, sa[n], 0, 0, 0);
      }
    }

    // ---- online softmax rows ----
    #pragma unroll
    for (int r = 0; r < 4; ++r) {
      const int qq = qrow_base + r;
      float sv[4];
      #pragma unroll
      for (int j = 0; j < 4; ++j) {
        const int kk = k0 + j * 16 + cl;
        const float vv = ((rmask >> (j * 4 + r)) & 1)
                             ? hv[j][r]
                             : sa[j][r] * 0.125f + hv[j][r];
        sv[j] = (kk <= qq && qq < Tn) ? vv : -3.0e38f;
      }
      float mx = fmaxf(fmaxf(sv[0], sv[1]), fmaxf(sv[2], sv[3]));
      mx = fmaxf(mx, __shfl_xor(mx, 1));
      mx = fmaxf(mx, __shfl_xor(mx, 2));
      mx = fmaxf(mx, __shfl_xor(mx, 4));
      mx = fmaxf(mx, __shfl_xor(mx, 8));
      const float mnew = fmaxf(mrow[r], mx);
      const float alpha = __expf(mrow[r] - mnew);
      mrow[r] = mnew;
      float ps[4], psum = 0.f;
      #pragma unroll
      for (int j = 0; j < 4; ++j) { ps[j] = __expf(sv[j] - mnew); psum += ps[j]; }
      psum += __shfl_xor(psum, 1);
      psum += __shfl_xor(psum, 2);
      psum += __shfl_xor(psum, 4);
      psum += __shfl_xor(psum, 8);
      lrow[r] = lrow[r] * alpha + psum;
      #pragma unroll
      for (int n = 0; n < 4; ++n) Oa[n][r] *= alpha;
      #pragma unroll
      for (int j = 0; j < 4; ++j)
        Ps[wave][j >> 1][(quad * 4 + r) * 32 + (j & 1) * 16 + cl] = f32_to_bf16(ps[j]);
    }

    // ---- O += P.V ----
    #pragma unroll
    for (int p = 0; p < 2; ++p) {
      const bf16x8 pa = *(const bf16x8*)(&Ps[wave][p][cl * 32 + quad * 8]);
      #pragma unroll
      for (int n = 0; n < 4; ++n) {
        const bf16x8 vb = *(const bf16x8*)(&Vs[p][(n * 16 + cl) * 32 + quad * 8]);
        Oa[n] = __builtin_amdgcn_mfma_f32_16x16x32_bf16(pa, vb, Oa[n], 0, 0, 0);
      }
    }
  }

  // ---- epilogue: ya[b,qq,hh*64+d] = O/l ----
  #pragma unroll
  for (int r = 0; r < 4; ++r) {
    const int qq = qrow_base + r;
    if (qq >= Tn) continue;
    const float inv = 1.f / lrow[r];
    u16* op = ya + ((size_t)(b * Tn + qq)) * Cn + hh * 64;
    #pragma unroll
    for (int n = 0; n < 4; ++n)
      op[n * 16 + cl] = f32_to_bf16(Oa[n][r] * inv);
  }
}

// ---------------------------------------------------------------------------
// bi_epi_ratio[b,i] = sum_h(mask_mean) / sum_h(mean)
// ---------------------------------------------------------------------------
__global__ __launch_bounds__(256)
void ratio_k(const float* __restrict__ mm, const float* __restrict__ am,
             float* __restrict__ out)
{
  const int idx = blockIdx.x * 256 + threadIdx.x;   // 0..1023
  const int b = idx >> 8, i = idx & 255;
  float smm = 0.f, sam = 0.f;
  #pragma unroll
  for (int hh = 0; hh < 16; ++hh) {
    smm += mm[(b * 16 + hh) * 256 + i];
    sam += am[(b * 16 + hh) * 256 + i];
  }
  out[idx] = smm / sam;
}

// ---------------------------------------------------------------------------
extern "C" void kernel_launch(void* const* d_in, const int* in_sizes, int n_in,
                              void* d_out, int out_size, void* d_ws, size_t ws_size,
                              hipStream_t stream)
{
  (void)in_sizes; (void)n_in; (void)out_size;

  const float* x   = (const float*)d_in[0];
  const float* xkv = (const float*)d_in[1];
  const float* hb  = (const float*)d_in[2];   // read-only
  const float* f01 = (const float*)d_in[3];
  const float* f02 = (const float*)d_in[4];
  const float* f12 = (const float*)d_in[5];
  const float* b01 = (const float*)d_in[6];
  const float* b02 = (const float*)d_in[7];
  const float* b12 = (const float*)d_in[8];
  const float* Wq  = (const float*)d_in[9];
  const float* Wk  = (const float*)d_in[10];
  const float* Wv  = (const float*)d_in[11];
  const float* Wp  = (const float*)d_in[12];
  const float* bq  = (const float*)d_in[13];
  const float* bk  = (const float*)d_in[14];
  const float* bv  = (const float*)d_in[15];
  const float* bp  = (const float*)d_in[16];
  float* out = (float*)d_out;

  // ---- workspace layout (no overlays, ~104.4 MiB) ----
  char* ws = (char*)d_ws;
  u16* xb   = (u16*)(ws + 0);            //  6,774,784
  u16* xkb  = (u16*)(ws + 6774784);      //  6,774,784
  u16* wqb  = (u16*)(ws + 13549568);     //  2,097,152
  u16* wkb  = (u16*)(ws + 15646720);
  u16* wvb  = (u16*)(ws + 17743872);
  u16* wpb  = (u16*)(ws + 19841024);
  u16* Qb   = (u16*)(ws + 21938176);     //  6,774,784
  u16* Kb   = (u16*)(ws + 28712960);
  u16* Vb   = (u16*)(ws + 35487744);
  u16* Vt   = (u16*)(ws + 42262528);     //  6,815,744
  u16* ya   = (u16*)(ws + 49078272);     //  6,774,784
  float* Sreg = (float*)(ws + 55853056); // 50,331,648 (192 x 256 x 256 fp32)
  float* bT = (float*)(ws + 106184704);  //  3,145,728
  float* mm = (float*)(ws + 109330432);  //     65,536
  float* am = (float*)(ws + 109395968);  //     65,536
  const size_t need = 109461504;
  if (ws_size < need) return;            // call-invariant; leaves out poisoned

  // 1) convert inputs/weights to bf16; transpose b matrices
  cvt_all_k<<<dim3(10712), 256, 0, stream>>>(x, xkv, Wq, Wk, Wv, Wp,
                                             xb, xkb, wqb, wkb, wvb, wpb);
  btrans_k<<<dim3(4, 4, 12), 256, 0, stream>>>(b01, b02, b12, bT);
  // 2) projections
  gemm_k<128,64,0><<<dim3(26,16,1),256,0,stream>>>(xb,  wqb, bq, nullptr, Qb, BTn, Cn, Cn, Cn, Cn, Cn);
  gemm_k<128,64,0><<<dim3(26,16,1),256,0,stream>>>(xkb, wkb, bk, nullptr, Kb, BTn, Cn, Cn, Cn, Cn, Cn);
  gemm_k<128,64,0><<<dim3(26,16,1),256,0,stream>>>(xkb, wvb, bv, nullptr, Vb, BTn, Cn, Cn, Cn, Cn, Cn);
  // 3) V transpose for PV B-operand
  vtrans_k<<<dim3(13,64),256,0,stream>>>(Vb, Vt);
  // 4) regional score blocks (Sreg = QK^T*SCALE + h)
  sreg_k<<<dim3(4,4,192),256,0,stream>>>(Qb, Kb, hb, Sreg);
  // 5) regional softmaxes + stats + multiplies + second softmaxes (on Sreg)
  regional_k<<<dim3(12288),256,0,stream>>>(Sreg, f01, f02, f12, bT, mm, am);
  // 6) fused flash attention -> ya
  flash_k<<<dim3(832),256,0,stream>>>(Qb, Kb, Vt, hb, Sreg, ya);
  // 7) y = y_att . Wp^T + bp -> d_out (fp32)
  gemm_k<128,64,3><<<dim3(26,16,1),256,0,stream>>>(ya, wpb, bp, out, nullptr, BTn, Cn, Cn, Cn, Cn, Cn);
  // 8) bi_epi_ratio -> d_out tail
  ratio_k<<<dim3(4),256,0,stream>>>(mm, am, out + YSZ);
}